// Round 1
// baseline (176.564 us; speedup 1.0000x reference)
//
#include <hip/hip_runtime.h>

#define NB 4
#define NC 6
#define NF 257
#define NT 2000
#define NPAIR 15
#define NACC 74   // [0..5] s_diag, [6..11] n_diag, [12+4p..] s_re,s_im,n_re,n_im, [72] sum_ms, [73] sum_mn
#define BLK 256

__global__ __launch_bounds__(BLK, 2) void mvdr_kernel(
    const float* __restrict__ sr, const float* __restrict__ si,
    const float* __restrict__ ms, const float* __restrict__ mn,
    float* __restrict__ out)
{
    constexpr int PC[NPAIR] = {0,0,0,0,0,1,1,1,1,2,2,2,3,3,4};
    constexpr int PE[NPAIR] = {1,2,3,4,5,2,3,4,5,3,4,5,4,5,5};

    const int bf = blockIdx.x;
    const int b  = bf / NF;
    const int f  = bf - b * NF;
    const int CS = NF * NT;                 // channel stride in spec
    const int sb = b * NC * CS + f * NT;    // spec base for (b, c=0, f)
    const int mb = (b * NF + f) * NT;       // mask / output base

    // ---------------- Phase 1: accumulate raw weighted PSDs ----------------
    float acc[NACC];
    #pragma unroll
    for (int i = 0; i < NACC; i++) acc[i] = 0.f;

    for (int t = threadIdx.x; t < NT; t += BLK) {
        const float vms = ms[mb + t];
        const float vmn = mn[mb + t];
        acc[72] += vms;
        acc[73] += vmn;
        float re[NC], im[NC];
        #pragma unroll
        for (int c = 0; c < NC; c++) {
            re[c] = sr[sb + c * CS + t];
            im[c] = si[sb + c * CS + t];
        }
        #pragma unroll
        for (int c = 0; c < NC; c++) {
            const float d = re[c] * re[c] + im[c] * im[c];
            acc[c]     += d * vms;
            acc[6 + c] += d * vmn;
        }
        #pragma unroll
        for (int p = 0; p < NPAIR; p++) {
            const int c = PC[p], e = PE[p];
            const float cr = re[c] * re[e] + im[c] * im[e];
            const float ci = im[c] * re[e] - re[c] * im[e];
            acc[12 + 4 * p + 0] += cr * vms;
            acc[12 + 4 * p + 1] += ci * vms;
            acc[12 + 4 * p + 2] += cr * vmn;
            acc[12 + 4 * p + 3] += ci * vmn;
        }
    }

    // ---------------- Reduction: wave shuffle, then 4-wave LDS combine -----
    #pragma unroll
    for (int i = 0; i < NACC; i++) {
        float v = acc[i];
        v += __shfl_down(v, 32);
        v += __shfl_down(v, 16);
        v += __shfl_down(v, 8);
        v += __shfl_down(v, 4);
        v += __shfl_down(v, 2);
        v += __shfl_down(v, 1);
        acc[i] = v;
    }

    __shared__ float red[4][NACC];
    __shared__ float s_wr[NC], s_wi[NC];   // conj(w)
    const int wid  = threadIdx.x >> 6;
    const int lane = threadIdx.x & 63;
    if (lane == 0) {
        #pragma unroll
        for (int i = 0; i < NACC; i++) red[wid][i] = acc[i];
    }
    __syncthreads();

    // ---------------- Solve (thread 0): X = A^-1 B, w = X[:,0]/tr ---------
    if (threadIdx.x == 0) {
        #define FIN(i) (red[0][i] + red[1][i] + red[2][i] + red[3][i])
        const float invS = 1.f / (FIN(72) + 1e-15f);
        const float invN = 1.f / (FIN(73) + 1e-15f);

        float Ar[NC][NC], Ai[NC][NC], Br[NC][NC], Bi[NC][NC];
        #pragma unroll
        for (int c = 0; c < NC; c++) {
            Br[c][c] = FIN(c) * invS;     Bi[c][c] = 0.f;
            Ar[c][c] = FIN(6 + c) * invN; Ai[c][c] = 0.f;
        }
        #pragma unroll
        for (int p = 0; p < NPAIR; p++) {
            const int c = PC[p], e = PE[p];
            const float sre = FIN(12 + 4 * p + 0) * invS;
            const float sim = FIN(12 + 4 * p + 1) * invS;
            const float nre = FIN(12 + 4 * p + 2) * invN;
            const float nim = FIN(12 + 4 * p + 3) * invN;
            Br[c][e] = sre;  Bi[c][e] = sim;
            Br[e][c] = sre;  Bi[e][c] = -sim;
            Ar[c][e] = nre;  Ai[c][e] = nim;
            Ar[e][c] = nre;  Ai[e][c] = -nim;
        }
        #undef FIN

        float trn = 0.f;
        #pragma unroll
        for (int c = 0; c < NC; c++) trn += Ar[c][c];
        const float eps = trn * 1e-7f + 1e-8f;
        #pragma unroll
        for (int c = 0; c < NC; c++) Ar[c][c] += eps;

        // Forward elimination (no pivoting: A is Hermitian positive definite)
        #pragma unroll
        for (int k = 0; k < NC; k++) {
            const float dr = Ar[k][k], di = Ai[k][k];
            const float idn = 1.f / (dr * dr + di * di);
            const float pr = dr * idn, pi = -di * idn;
            #pragma unroll
            for (int i2 = k + 1; i2 < NC; i2++) {
                const float fr = Ar[i2][k] * pr - Ai[i2][k] * pi;
                const float fi = Ar[i2][k] * pi + Ai[i2][k] * pr;
                #pragma unroll
                for (int j = k + 1; j < NC; j++) {
                    Ar[i2][j] -= fr * Ar[k][j] - fi * Ai[k][j];
                    Ai[i2][j] -= fr * Ai[k][j] + fi * Ar[k][j];
                }
                #pragma unroll
                for (int j = 0; j < NC; j++) {
                    Br[i2][j] -= fr * Br[k][j] - fi * Bi[k][j];
                    Bi[i2][j] -= fr * Bi[k][j] + fi * Br[k][j];
                }
            }
        }
        // Back substitution, in place into B (B becomes X)
        #pragma unroll
        for (int k = NC - 1; k >= 0; k--) {
            const float dr = Ar[k][k], di = Ai[k][k];
            const float idn = 1.f / (dr * dr + di * di);
            const float pr = dr * idn, pi = -di * idn;
            #pragma unroll
            for (int j = 0; j < NC; j++) {
                float xr = Br[k][j], xi = Bi[k][j];
                #pragma unroll
                for (int m = k + 1; m < NC; m++) {
                    xr -= Ar[k][m] * Br[m][j] - Ai[k][m] * Bi[m][j];
                    xi -= Ar[k][m] * Bi[m][j] + Ai[k][m] * Br[m][j];
                }
                Br[k][j] = xr * pr - xi * pi;
                Bi[k][j] = xr * pi + xi * pr;
            }
        }

        float trr = 1e-8f, tri = 0.f;   // TIK_EPS added to real part of trace
        #pragma unroll
        for (int c = 0; c < NC; c++) { trr += Br[c][c]; tri += Bi[c][c]; }
        const float idn = 1.f / (trr * trr + tri * tri);
        #pragma unroll
        for (int c = 0; c < NC; c++) {
            const float xr = Br[c][0], xi = Bi[c][0];
            const float wre = (xr * trr + xi * tri) * idn;
            const float wim = (xi * trr - xr * tri) * idn;
            s_wr[c] = wre;
            s_wi[c] = -wim;   // store conj(w)
        }
    }
    __syncthreads();

    // ---------------- Phase 2: enh[t] = sum_c conj(w[c]) * spec[c,t] -------
    float wr[NC], wi[NC];
    #pragma unroll
    for (int c = 0; c < NC; c++) { wr[c] = s_wr[c]; wi[c] = s_wi[c]; }

    float2* o2 = (float2*)out;
    for (int t = threadIdx.x; t < NT; t += BLK) {
        float er = 0.f, ei = 0.f;
        #pragma unroll
        for (int c = 0; c < NC; c++) {
            const float a  = sr[sb + c * CS + t];
            const float bb = si[sb + c * CS + t];
            er += wr[c] * a - wi[c] * bb;
            ei += wr[c] * bb + wi[c] * a;
        }
        o2[mb + t] = make_float2(er, ei);
    }
}

extern "C" void kernel_launch(void* const* d_in, const int* in_sizes, int n_in,
                              void* d_out, int out_size, void* d_ws, size_t ws_size,
                              hipStream_t stream) {
    const float* sr = (const float*)d_in[0];
    const float* si = (const float*)d_in[1];
    const float* ms = (const float*)d_in[2];
    const float* mn = (const float*)d_in[3];
    float* out = (float*)d_out;
    mvdr_kernel<<<NB * NF, BLK, 0, stream>>>(sr, si, ms, mn, out);
}